// Round 1
// baseline (4405.465 us; speedup 1.0000x reference)
//
#include <hip/hip_runtime.h>
#include <math.h>

#define NUM_DRUG 50000
#define NUM_CELL 20000
#define HDIM 128
#define NE 600000
#define NB 4096
#define LN_EPS 1e-5f

// ---------------------------------------------------------------------------
// counts: cnt_c[dst] over dt edges, cnt_d[dst] over td edges (fixed per call)
// ---------------------------------------------------------------------------
__global__ void count_kernel(const int* __restrict__ dt_dst, const int* __restrict__ td_dst,
                             float* __restrict__ cnt_c, float* __restrict__ cnt_d, int ne) {
    int t = blockIdx.x * blockDim.x + threadIdx.x;
    if (t < ne) {
        unsafeAtomicAdd(&cnt_c[dt_dst[t]], 1.0f);
    } else if (t < 2 * ne) {
        unsafeAtomicAdd(&cnt_d[td_dst[t - ne]], 1.0f);
    }
}

// ---------------------------------------------------------------------------
// scatter-add of raw embedding rows: agg[dst] += h[src]
// one thread per float4 (32 threads per edge) -> coalesced 16B gather
// ---------------------------------------------------------------------------
__global__ void scatter_add_kernel(const float* __restrict__ hsrc, const int* __restrict__ src,
                                   const int* __restrict__ dst, float* __restrict__ agg, int ne) {
    int t = blockIdx.x * blockDim.x + threadIdx.x;
    if (t >= ne * 32) return;
    int e = t >> 5;
    int c = (t & 31) << 2;  // float offset 0..124
    int s = src[e], d = dst[e];
    const float4 v = *(const float4*)(hsrc + (size_t)s * HDIM + c);
    float* p = agg + (size_t)d * HDIM + c;
    unsafeAtomicAdd(p + 0, v.x);
    unsafeAtomicAdd(p + 1, v.y);
    unsafeAtomicAdd(p + 2, v.z);
    unsafeAtomicAdd(p + 3, v.w);
}

// ---------------------------------------------------------------------------
// in-place msg = (agg / max(cnt,1)) @ W^T    (W stored [out][in] row-major)
// block = 256 threads, 32 rows per block. X tile staged (scaled) in LDS.
// thread (j = tid&127, rowgroup = (tid>>7)*16) computes 16 outputs at col j.
// Xs reads are wave-uniform (broadcast, no bank conflict); W read via float4
// from global (64KB, L1/L2 resident).
// ---------------------------------------------------------------------------
__global__ void msg_gemm_kernel(float* __restrict__ agg, const float* __restrict__ cnt,
                                const float* __restrict__ W, int nrows) {
    __shared__ float4 Xs[32][32];  // 32 rows x 128 floats = 16 KB
    const int tid = threadIdx.x;
    const int r0 = blockIdx.x * 32;

    // stage + scale by 1/max(cnt,1)
    for (int i = tid; i < 32 * 32; i += 256) {
        int r = i >> 5, k4 = i & 31;
        int row = r0 + r;
        float4 v = make_float4(0.f, 0.f, 0.f, 0.f);
        if (row < nrows) {
            v = ((const float4*)agg)[row * 32 + k4];
            float sc = 1.0f / fmaxf(cnt[row], 1.0f);
            v.x *= sc; v.y *= sc; v.z *= sc; v.w *= sc;
        }
        Xs[r][k4] = v;
    }
    __syncthreads();

    const int j = tid & 127;
    const int rg = (tid >> 7) * 16;
    float acc[16];
#pragma unroll
    for (int r = 0; r < 16; ++r) acc[r] = 0.f;

    const float4* W4 = (const float4*)(W + j * HDIM);
    for (int k4 = 0; k4 < 32; ++k4) {
        float4 w = W4[k4];
#pragma unroll
        for (int r = 0; r < 16; ++r) {
            float4 x = Xs[rg + r][k4];
            acc[r] += x.x * w.x + x.y * w.y + x.z * w.z + x.w * w.w;
        }
    }

    // all global reads of this block's rows happened before the sync; in-place write is safe
#pragma unroll
    for (int r = 0; r < 16; ++r) {
        int row = r0 + rg + r;
        if (row < nrows) agg[(size_t)row * HDIM + j] = acc[r];
    }
}

// ---------------------------------------------------------------------------
// h_out = relu(layernorm(h_in + msg) * g + b), one wave per row (128 elems)
// ---------------------------------------------------------------------------
__global__ void ln_relu_kernel(const float* __restrict__ hin, const float* __restrict__ msg,
                               const float* __restrict__ g, const float* __restrict__ b,
                               float* __restrict__ hout, int nrows) {
    int wave = (blockIdx.x * blockDim.x + threadIdx.x) >> 6;
    int lane = threadIdx.x & 63;
    if (wave >= nrows) return;
    const float2 a = ((const float2*)(hin + (size_t)wave * HDIM))[lane];
    const float2 m = ((const float2*)(msg + (size_t)wave * HDIM))[lane];
    float t0 = a.x + m.x, t1 = a.y + m.y;
    float s1 = t0 + t1;
    float s2 = t0 * t0 + t1 * t1;
#pragma unroll
    for (int o = 32; o; o >>= 1) {
        s1 += __shfl_xor(s1, o);
        s2 += __shfl_xor(s2, o);
    }
    float mu = s1 * (1.0f / 128.0f);
    float var = s2 * (1.0f / 128.0f) - mu * mu;
    float rs = rsqrtf(var + LN_EPS);
    float2 gg = ((const float2*)g)[lane];
    float2 bb = ((const float2*)b)[lane];
    float y0 = fmaxf((t0 - mu) * rs * gg.x + bb.x, 0.f);
    float y1 = fmaxf((t1 - mu) * rs * gg.y + bb.y, 0.f);
    ((float2*)(hout + (size_t)wave * HDIM))[lane] = make_float2(y0, y1);
}

// ---------------------------------------------------------------------------
// out[i] = sigmoid(dot(hd[drug_ids[i]], wf[0:128]) + dot(hc[cell_ids[i]], wf[128:256]) + bf)
// one wave per output
// ---------------------------------------------------------------------------
__global__ void final_kernel(const float* __restrict__ hd, const float* __restrict__ hc,
                             const int* __restrict__ did, const int* __restrict__ cid,
                             const float* __restrict__ wf, const float* __restrict__ bf,
                             float* __restrict__ out, int nb) {
    int row = (blockIdx.x * blockDim.x + threadIdx.x) >> 6;
    int lane = threadIdx.x & 63;
    if (row >= nb) return;
    int d = did[row], c = cid[row];
    float2 x = ((const float2*)(hd + (size_t)d * HDIM))[lane];
    float2 y = ((const float2*)(hc + (size_t)c * HDIM))[lane];
    float2 wa = ((const float2*)wf)[lane];
    float2 wb = ((const float2*)(wf + HDIM))[lane];
    float s = x.x * wa.x + x.y * wa.y + y.x * wb.x + y.y * wb.y;
#pragma unroll
    for (int o = 32; o; o >>= 1) s += __shfl_xor(s, o);
    if (lane == 0) out[row] = 1.0f / (1.0f + expf(-(s + bf[0])));
}

// ---------------------------------------------------------------------------
extern "C" void kernel_launch(void* const* d_in, const int* in_sizes, int n_in,
                              void* d_out, int out_size, void* d_ws, size_t ws_size,
                              hipStream_t stream) {
    const float* emb_drug = (const float*)d_in[0];
    const float* emb_cell = (const float*)d_in[1];
    const float* W_dt     = (const float*)d_in[2];
    const float* W_td     = (const float*)d_in[3];
    const float* g_d      = (const float*)d_in[4];
    const float* b_d      = (const float*)d_in[5];
    const float* g_c      = (const float*)d_in[6];
    const float* b_c      = (const float*)d_in[7];
    const float* Wf       = (const float*)d_in[8];
    const float* bf       = (const float*)d_in[9];
    const int* dt_src     = (const int*)d_in[10];
    const int* dt_dst     = (const int*)d_in[11];
    const int* td_src     = (const int*)d_in[12];
    const int* td_dst     = (const int*)d_in[13];
    const int* drug_ids   = (const int*)d_in[14];
    const int* cell_ids   = (const int*)d_in[15];
    float* out = (float*)d_out;

    // workspace layout (floats): [agg_d][agg_c][cnt_d][cnt_c][hd][hc]  ~= 72 MB
    float* ws    = (float*)d_ws;
    float* agg_d = ws;
    float* agg_c = agg_d + (size_t)NUM_DRUG * HDIM;
    float* cnt_d = agg_c + (size_t)NUM_CELL * HDIM;
    float* cnt_c = cnt_d + NUM_DRUG;
    float* hd    = cnt_c + NUM_CELL;
    float* hc    = hd + (size_t)NUM_DRUG * HDIM;

    const size_t agg_bytes  = ((size_t)NUM_DRUG * HDIM + (size_t)NUM_CELL * HDIM) * sizeof(float);
    const size_t zero_bytes = agg_bytes + (NUM_DRUG + NUM_CELL) * sizeof(float);

    const dim3 B(256);
    const int scatter_blocks = (NE * 32) / 256;  // 75000 exact
    const int gemm_blocks_d  = (NUM_DRUG + 31) / 32;
    const int gemm_blocks_c  = (NUM_CELL + 31) / 32;
    const int ln_blocks_d    = (NUM_DRUG * 64) / 256;
    const int ln_blocks_c    = (NUM_CELL * 64) / 256;

    // zero aggs + counts (ws is poisoned 0xAA before every call)
    hipMemsetAsync(d_ws, 0, zero_bytes, stream);

    count_kernel<<<(2 * NE + 255) / 256, B, 0, stream>>>(dt_dst, td_dst, cnt_c, cnt_d, NE);

    // ---- layer 1 (reads emb_*, writes hd/hc) ----
    scatter_add_kernel<<<scatter_blocks, B, 0, stream>>>(emb_drug, dt_src, dt_dst, agg_c, NE);
    scatter_add_kernel<<<scatter_blocks, B, 0, stream>>>(emb_cell, td_src, td_dst, agg_d, NE);
    msg_gemm_kernel<<<gemm_blocks_c, B, 0, stream>>>(agg_c, cnt_c, W_dt, NUM_CELL);
    msg_gemm_kernel<<<gemm_blocks_d, B, 0, stream>>>(agg_d, cnt_d, W_td, NUM_DRUG);
    ln_relu_kernel<<<ln_blocks_d, B, 0, stream>>>(emb_drug, agg_d, g_d, b_d, hd, NUM_DRUG);
    ln_relu_kernel<<<ln_blocks_c, B, 0, stream>>>(emb_cell, agg_c, g_c, b_c, hc, NUM_CELL);

    // ---- layer 2 (reads hd/hc, updates them in place row-wise) ----
    hipMemsetAsync(d_ws, 0, agg_bytes, stream);
    scatter_add_kernel<<<scatter_blocks, B, 0, stream>>>(hd, dt_src, dt_dst, agg_c, NE);
    scatter_add_kernel<<<scatter_blocks, B, 0, stream>>>(hc, td_src, td_dst, agg_d, NE);
    msg_gemm_kernel<<<gemm_blocks_c, B, 0, stream>>>(agg_c, cnt_c, W_dt, NUM_CELL);
    msg_gemm_kernel<<<gemm_blocks_d, B, 0, stream>>>(agg_d, cnt_d, W_td, NUM_DRUG);
    ln_relu_kernel<<<ln_blocks_d, B, 0, stream>>>(hd, agg_d, g_d, b_d, hd, NUM_DRUG);
    ln_relu_kernel<<<ln_blocks_c, B, 0, stream>>>(hc, agg_c, g_c, b_c, hc, NUM_CELL);

    final_kernel<<<(NB * 64) / 256, B, 0, stream>>>(hd, hc, drug_ids, cell_ids, Wf, bf, out, NB);
}

// Round 2
// 642.869 us; speedup vs baseline: 6.8528x; 6.8528x over previous
//
#include <hip/hip_runtime.h>
#include <math.h>

#define NUM_DRUG 50000
#define NUM_CELL 20000
#define HDIM 128
#define NE 600000
#define NB 4096
#define LN_EPS 1e-5f

// ---------------------------------------------------------------------------
// histogram of dst indices for both relations (int atomics, cheap)
// ---------------------------------------------------------------------------
__global__ void hist_kernel(const int* __restrict__ dt_dst, const int* __restrict__ td_dst,
                            int* __restrict__ cnt_c, int* __restrict__ cnt_d, int ne) {
    int t = blockIdx.x * blockDim.x + threadIdx.x;
    if (t < ne) {
        atomicAdd(&cnt_c[dt_dst[t]], 1);
    } else if (t < 2 * ne) {
        atomicAdd(&cnt_d[td_dst[t - ne]], 1);
    }
}

// ---------------------------------------------------------------------------
// single-block exclusive prefix scan (1024 threads); block 0 -> cell counts,
// block 1 -> drug counts. rs has n+1 entries (rs[n] = total).
// ---------------------------------------------------------------------------
__global__ void scan_kernel(const int* __restrict__ cnt0, int* __restrict__ rs0, int n0,
                            const int* __restrict__ cnt1, int* __restrict__ rs1, int n1) {
    const int* cnt = blockIdx.x ? cnt1 : cnt0;
    int* rs = blockIdx.x ? rs1 : rs0;
    int n = blockIdx.x ? n1 : n0;

    __shared__ int wsum[16];
    __shared__ int s_carry;
    const int tid = threadIdx.x;
    const int lane = tid & 63;
    const int w = tid >> 6;
    if (tid == 0) s_carry = 0;
    __syncthreads();

    for (int base = 0; base < n; base += 1024) {
        int v = (base + tid < n) ? cnt[base + tid] : 0;
        int x = v;
#pragma unroll
        for (int o = 1; o < 64; o <<= 1) {
            int y = __shfl_up(x, o);
            if (lane >= o) x += y;
        }
        if (lane == 63) wsum[w] = x;
        __syncthreads();
        if (w == 0 && lane < 16) {
            int y = wsum[lane];
#pragma unroll
            for (int o = 1; o < 16; o <<= 1) {
                int z = __shfl_up(y, o);
                if (lane >= o) y += z;
            }
            wsum[lane] = y;
        }
        __syncthreads();
        int total = wsum[15];
        int excl = s_carry + (w ? wsum[w - 1] : 0) + x - v;
        if (base + tid < n) rs[base + tid] = excl;
        __syncthreads();
        if (tid == 0) s_carry += total;
        __syncthreads();
    }
    if (tid == 0) rs[n] = s_carry;
}

// ---------------------------------------------------------------------------
// fill CSR: csr[rs[dst] + pos] = src  (pos via int atomic on cursor)
// ---------------------------------------------------------------------------
__global__ void fill_kernel(const int* __restrict__ dt_src, const int* __restrict__ dt_dst,
                            const int* __restrict__ td_src, const int* __restrict__ td_dst,
                            const int* __restrict__ rs_c, const int* __restrict__ rs_d,
                            int* __restrict__ cur_c, int* __restrict__ cur_d,
                            int* __restrict__ csr_dt, int* __restrict__ csr_td, int ne) {
    int t = blockIdx.x * blockDim.x + threadIdx.x;
    if (t < ne) {
        int d = dt_dst[t];
        int p = atomicAdd(&cur_c[d], 1);
        csr_dt[rs_c[d] + p] = dt_src[t];
    } else if (t < 2 * ne) {
        int e = t - ne;
        int d = td_dst[e];
        int p = atomicAdd(&cur_d[d], 1);
        csr_td[rs_d[d] + p] = td_src[e];
    }
}

// ---------------------------------------------------------------------------
// gather-aggregate mean: one wave per dst row, 2 floats per lane.
// agg[d] = sum_{e in row d} h[csr[e]] / max(deg,1)
// ---------------------------------------------------------------------------
__global__ void agg_kernel(const float* __restrict__ h, const int* __restrict__ csr,
                           const int* __restrict__ rs, float* __restrict__ agg, int nrows) {
    int wave = (blockIdx.x * blockDim.x + threadIdx.x) >> 6;
    int lane = threadIdx.x & 63;
    if (wave >= nrows) return;
    int beg = rs[wave], end = rs[wave + 1];
    float ax = 0.f, ay = 0.f, bx = 0.f, by = 0.f;
    int e = beg;
    for (; e + 1 < end; e += 2) {
        int s0 = csr[e], s1 = csr[e + 1];
        float2 v0 = ((const float2*)(h + (size_t)s0 * HDIM))[lane];
        float2 v1 = ((const float2*)(h + (size_t)s1 * HDIM))[lane];
        ax += v0.x; ay += v0.y;
        bx += v1.x; by += v1.y;
    }
    if (e < end) {
        int s0 = csr[e];
        float2 v0 = ((const float2*)(h + (size_t)s0 * HDIM))[lane];
        ax += v0.x; ay += v0.y;
    }
    float inv = 1.0f / fmaxf((float)(end - beg), 1.0f);
    ((float2*)(agg + (size_t)wave * HDIM))[lane] = make_float2((ax + bx) * inv, (ay + by) * inv);
}

// ---------------------------------------------------------------------------
// in-place msg = agg @ W^T  (W stored [out][in] row-major; mean already folded)
// ---------------------------------------------------------------------------
__global__ void msg_gemm_kernel(float* __restrict__ agg, const float* __restrict__ W, int nrows) {
    __shared__ float4 Xs[32][32];  // 32 rows x 128 floats = 16 KB
    const int tid = threadIdx.x;
    const int r0 = blockIdx.x * 32;

    for (int i = tid; i < 32 * 32; i += 256) {
        int r = i >> 5, k4 = i & 31;
        int row = r0 + r;
        float4 v = make_float4(0.f, 0.f, 0.f, 0.f);
        if (row < nrows) v = ((const float4*)agg)[row * 32 + k4];
        Xs[r][k4] = v;
    }
    __syncthreads();

    const int j = tid & 127;
    const int rg = (tid >> 7) * 16;
    float acc[16];
#pragma unroll
    for (int r = 0; r < 16; ++r) acc[r] = 0.f;

    const float4* W4 = (const float4*)(W + j * HDIM);
    for (int k4 = 0; k4 < 32; ++k4) {
        float4 w = W4[k4];
#pragma unroll
        for (int r = 0; r < 16; ++r) {
            float4 x = Xs[rg + r][k4];
            acc[r] += x.x * w.x + x.y * w.y + x.z * w.z + x.w * w.w;
        }
    }

#pragma unroll
    for (int r = 0; r < 16; ++r) {
        int row = r0 + rg + r;
        if (row < nrows) agg[(size_t)row * HDIM + j] = acc[r];
    }
}

// ---------------------------------------------------------------------------
// h_out = relu(layernorm(h_in + msg) * g + b), one wave per row (128 elems)
// ---------------------------------------------------------------------------
__global__ void ln_relu_kernel(const float* __restrict__ hin, const float* __restrict__ msg,
                               const float* __restrict__ g, const float* __restrict__ b,
                               float* __restrict__ hout, int nrows) {
    int wave = (blockIdx.x * blockDim.x + threadIdx.x) >> 6;
    int lane = threadIdx.x & 63;
    if (wave >= nrows) return;
    const float2 a = ((const float2*)(hin + (size_t)wave * HDIM))[lane];
    const float2 m = ((const float2*)(msg + (size_t)wave * HDIM))[lane];
    float t0 = a.x + m.x, t1 = a.y + m.y;
    float s1 = t0 + t1;
    float s2 = t0 * t0 + t1 * t1;
#pragma unroll
    for (int o = 32; o; o >>= 1) {
        s1 += __shfl_xor(s1, o);
        s2 += __shfl_xor(s2, o);
    }
    float mu = s1 * (1.0f / 128.0f);
    float var = s2 * (1.0f / 128.0f) - mu * mu;
    float rs = rsqrtf(var + LN_EPS);
    float2 gg = ((const float2*)g)[lane];
    float2 bb = ((const float2*)b)[lane];
    float y0 = fmaxf((t0 - mu) * rs * gg.x + bb.x, 0.f);
    float y1 = fmaxf((t1 - mu) * rs * gg.y + bb.y, 0.f);
    ((float2*)(hout + (size_t)wave * HDIM))[lane] = make_float2(y0, y1);
}

// ---------------------------------------------------------------------------
// out[i] = sigmoid(dot(hd[did[i]], wf[0:128]) + dot(hc[cid[i]], wf[128:256]) + bf)
// ---------------------------------------------------------------------------
__global__ void final_kernel(const float* __restrict__ hd, const float* __restrict__ hc,
                             const int* __restrict__ did, const int* __restrict__ cid,
                             const float* __restrict__ wf, const float* __restrict__ bf,
                             float* __restrict__ out, int nb) {
    int row = (blockIdx.x * blockDim.x + threadIdx.x) >> 6;
    int lane = threadIdx.x & 63;
    if (row >= nb) return;
    int d = did[row], c = cid[row];
    float2 x = ((const float2*)(hd + (size_t)d * HDIM))[lane];
    float2 y = ((const float2*)(hc + (size_t)c * HDIM))[lane];
    float2 wa = ((const float2*)wf)[lane];
    float2 wb = ((const float2*)(wf + HDIM))[lane];
    float s = x.x * wa.x + x.y * wa.y + y.x * wb.x + y.y * wb.y;
#pragma unroll
    for (int o = 32; o; o >>= 1) s += __shfl_xor(s, o);
    if (lane == 0) out[row] = 1.0f / (1.0f + expf(-(s + bf[0])));
}

// ---------------------------------------------------------------------------
extern "C" void kernel_launch(void* const* d_in, const int* in_sizes, int n_in,
                              void* d_out, int out_size, void* d_ws, size_t ws_size,
                              hipStream_t stream) {
    const float* emb_drug = (const float*)d_in[0];
    const float* emb_cell = (const float*)d_in[1];
    const float* W_dt     = (const float*)d_in[2];
    const float* W_td     = (const float*)d_in[3];
    const float* g_d      = (const float*)d_in[4];
    const float* b_d      = (const float*)d_in[5];
    const float* g_c      = (const float*)d_in[6];
    const float* b_c      = (const float*)d_in[7];
    const float* Wf       = (const float*)d_in[8];
    const float* bf       = (const float*)d_in[9];
    const int* dt_src     = (const int*)d_in[10];
    const int* dt_dst     = (const int*)d_in[11];
    const int* td_src     = (const int*)d_in[12];
    const int* td_dst     = (const int*)d_in[13];
    const int* drug_ids   = (const int*)d_in[14];
    const int* cell_ids   = (const int*)d_in[15];
    float* out = (float*)d_out;

    // ---- workspace layout ----
    // [cnt_c 20000][cnt_d 50000][cur_c 20000][cur_d 50000]  <- zeroed (560 KB)
    // [rs_c 20001][rs_d 50001][csr_dt 600000][csr_td 600000]
    // [bufA_d][bufB_d][bufA_c][bufB_c]  (float, 128-wide rows)
    int* cnt_c  = (int*)d_ws;
    int* cnt_d  = cnt_c + NUM_CELL;
    int* cur_c  = cnt_d + NUM_DRUG;
    int* cur_d  = cur_c + NUM_CELL;
    int* rs_c   = cur_d + NUM_DRUG;
    int* rs_d   = rs_c + (NUM_CELL + 1);
    int* csr_dt = rs_d + (NUM_DRUG + 1);
    int* csr_td = csr_dt + NE;
    size_t off  = (size_t)(csr_td + NE - (int*)d_ws);
    off = (off + 63) & ~(size_t)63;  // 256B-align the float buffers
    float* bufA_d = (float*)d_ws + off;
    float* bufB_d = bufA_d + (size_t)NUM_DRUG * HDIM;
    float* bufA_c = bufB_d + (size_t)NUM_DRUG * HDIM;
    float* bufB_c = bufA_c + (size_t)NUM_CELL * HDIM;

    const dim3 B(256);
    const int gemm_blocks_d = (NUM_DRUG + 31) / 32;
    const int gemm_blocks_c = (NUM_CELL + 31) / 32;
    const int ln_blocks_d   = (NUM_DRUG * 64) / 256;
    const int ln_blocks_c   = (NUM_CELL * 64) / 256;
    const int agg_blocks_d  = (NUM_DRUG * 64 + 255) / 256;
    const int agg_blocks_c  = (NUM_CELL * 64 + 255) / 256;

    // ---- build CSR (once, reused by both layers) ----
    hipMemsetAsync(d_ws, 0, (size_t)(2 * (NUM_CELL + NUM_DRUG)) * sizeof(int), stream);
    hist_kernel<<<(2 * NE + 255) / 256, B, 0, stream>>>(dt_dst, td_dst, cnt_c, cnt_d, NE);
    scan_kernel<<<2, 1024, 0, stream>>>(cnt_c, rs_c, NUM_CELL, cnt_d, rs_d, NUM_DRUG);
    fill_kernel<<<(2 * NE + 255) / 256, B, 0, stream>>>(dt_src, dt_dst, td_src, td_dst,
                                                        rs_c, rs_d, cur_c, cur_d,
                                                        csr_dt, csr_td, NE);

    // ---- layer 1: read emb_*, write bufA_* ----
    agg_kernel<<<agg_blocks_c, B, 0, stream>>>(emb_drug, csr_dt, rs_c, bufA_c, NUM_CELL);
    agg_kernel<<<agg_blocks_d, B, 0, stream>>>(emb_cell, csr_td, rs_d, bufA_d, NUM_DRUG);
    msg_gemm_kernel<<<gemm_blocks_c, B, 0, stream>>>(bufA_c, W_dt, NUM_CELL);
    msg_gemm_kernel<<<gemm_blocks_d, B, 0, stream>>>(bufA_d, W_td, NUM_DRUG);
    ln_relu_kernel<<<ln_blocks_d, B, 0, stream>>>(emb_drug, bufA_d, g_d, b_d, bufA_d, NUM_DRUG);
    ln_relu_kernel<<<ln_blocks_c, B, 0, stream>>>(emb_cell, bufA_c, g_c, b_c, bufA_c, NUM_CELL);

    // ---- layer 2: read bufA_*, write bufB_* ----
    agg_kernel<<<agg_blocks_c, B, 0, stream>>>(bufA_d, csr_dt, rs_c, bufB_c, NUM_CELL);
    agg_kernel<<<agg_blocks_d, B, 0, stream>>>(bufA_c, csr_td, rs_d, bufB_d, NUM_DRUG);
    msg_gemm_kernel<<<gemm_blocks_c, B, 0, stream>>>(bufB_c, W_dt, NUM_CELL);
    msg_gemm_kernel<<<gemm_blocks_d, B, 0, stream>>>(bufB_d, W_td, NUM_DRUG);
    ln_relu_kernel<<<ln_blocks_d, B, 0, stream>>>(bufA_d, bufB_d, g_d, b_d, bufB_d, NUM_DRUG);
    ln_relu_kernel<<<ln_blocks_c, B, 0, stream>>>(bufA_c, bufB_c, g_c, b_c, bufB_c, NUM_CELL);

    final_kernel<<<(NB * 64) / 256, B, 0, stream>>>(bufB_d, bufB_c, drug_ids, cell_ids, Wf, bf, out, NB);
}

// Round 3
// 571.461 us; speedup vs baseline: 7.7091x; 1.1250x over previous
//
#include <hip/hip_runtime.h>
#include <math.h>

#define NUM_DRUG 50000
#define NUM_CELL 20000
#define HDIM 128
#define NE 600000
#define NB 4096
#define LN_EPS 1e-5f

#define CELL_BLOCKS ((NUM_CELL + 31) / 32)   // 625
#define DRUG_BLOCKS ((NUM_DRUG + 31) / 32)   // 1563

// ---------------------------------------------------------------------------
// histogram of dst indices for both relations (int atomics, L2-resident)
// ---------------------------------------------------------------------------
__global__ void hist_kernel(const int* __restrict__ dt_dst, const int* __restrict__ td_dst,
                            int* __restrict__ cnt_c, int* __restrict__ cnt_d, int ne) {
    int t = blockIdx.x * blockDim.x + threadIdx.x;
    if (t < ne) {
        atomicAdd(&cnt_c[dt_dst[t]], 1);
    } else if (t < 2 * ne) {
        atomicAdd(&cnt_d[td_dst[t - ne]], 1);
    }
}

// ---------------------------------------------------------------------------
// single-block exclusive prefix scan; writes rs (n+1 entries) AND cur (= rs copy,
// used as absolute cursors by fill). block 0 -> cell, block 1 -> drug.
// ---------------------------------------------------------------------------
__global__ void scan_kernel(const int* __restrict__ cnt0, int* __restrict__ rs0, int* __restrict__ cur0, int n0,
                            const int* __restrict__ cnt1, int* __restrict__ rs1, int* __restrict__ cur1, int n1) {
    const int* cnt = blockIdx.x ? cnt1 : cnt0;
    int* rs  = blockIdx.x ? rs1 : rs0;
    int* cur = blockIdx.x ? cur1 : cur0;
    int n = blockIdx.x ? n1 : n0;

    __shared__ int wsum[16];
    __shared__ int s_carry;
    const int tid = threadIdx.x;
    const int lane = tid & 63;
    const int w = tid >> 6;
    if (tid == 0) s_carry = 0;
    __syncthreads();

    for (int base = 0; base < n; base += 1024) {
        int v = (base + tid < n) ? cnt[base + tid] : 0;
        int x = v;
#pragma unroll
        for (int o = 1; o < 64; o <<= 1) {
            int y = __shfl_up(x, o);
            if (lane >= o) x += y;
        }
        if (lane == 63) wsum[w] = x;
        __syncthreads();
        if (w == 0 && lane < 16) {
            int y = wsum[lane];
#pragma unroll
            for (int o = 1; o < 16; o <<= 1) {
                int z = __shfl_up(y, o);
                if (lane >= o) y += z;
            }
            wsum[lane] = y;
        }
        __syncthreads();
        int total = wsum[15];
        int excl = s_carry + (w ? wsum[w - 1] : 0) + x - v;
        if (base + tid < n) { rs[base + tid] = excl; cur[base + tid] = excl; }
        __syncthreads();
        if (tid == 0) s_carry += total;
        __syncthreads();
    }
    if (tid == 0) rs[n] = s_carry;
}

// ---------------------------------------------------------------------------
// fill CSR: csr[atomicAdd(&cur[dst],1)] = src   (cur pre-initialized to rs)
// ---------------------------------------------------------------------------
__global__ void fill_kernel(const int* __restrict__ dt_src, const int* __restrict__ dt_dst,
                            const int* __restrict__ td_src, const int* __restrict__ td_dst,
                            int* __restrict__ cur_c, int* __restrict__ cur_d,
                            int* __restrict__ csr_dt, int* __restrict__ csr_td, int ne) {
    int t = blockIdx.x * blockDim.x + threadIdx.x;
    if (t < ne) {
        int s = dt_src[t];
        int p = atomicAdd(&cur_c[dt_dst[t]], 1);
        csr_dt[p] = s;
    } else if (t < 2 * ne) {
        int e = t - ne;
        int s = td_src[e];
        int p = atomicAdd(&cur_d[td_dst[e]], 1);
        csr_td[p] = s;
    }
}

// ---------------------------------------------------------------------------
// fused layer: agg(mean gather) -> @W^T -> residual+LN+ReLU, both relations
// in one dispatch. blocks [0,CELL_BLOCKS) update cells, rest update drugs.
// 256 threads, 32 dst rows per block, 16 KB LDS tile.
// ---------------------------------------------------------------------------
__global__ void layer_kernel(const float* __restrict__ hA,      // drug-side input table
                             const float* __restrict__ hB,      // cell-side input table
                             const int* __restrict__ csr_dt, const int* __restrict__ rs_c,
                             const int* __restrict__ csr_td, const int* __restrict__ rs_d,
                             const float* __restrict__ W_dt, const float* __restrict__ W_td,
                             const float* __restrict__ g_c, const float* __restrict__ b_c,
                             const float* __restrict__ g_d, const float* __restrict__ b_d,
                             float* __restrict__ out_c, float* __restrict__ out_d) {
    __shared__ __align__(16) float Xs[32][128];

    const bool isCell = blockIdx.x < CELL_BLOCKS;
    const float* hsrc = isCell ? hA : hB;
    const float* hres = isCell ? hB : hA;
    const int* csr = isCell ? csr_dt : csr_td;
    const int* rs  = isCell ? rs_c : rs_d;
    const float* W = isCell ? W_dt : W_td;
    const float* g = isCell ? g_c : g_d;
    const float* b = isCell ? b_c : b_d;
    float* hout = isCell ? out_c : out_d;
    const int nrows = isCell ? NUM_CELL : NUM_DRUG;
    const int r0 = (isCell ? blockIdx.x : blockIdx.x - CELL_BLOCKS) * 32;

    const int tid = threadIdx.x;
    const int lane = tid & 63;
    const int w = tid >> 6;       // wave 0..3
    const int half = lane >> 5;   // 0: even edges, 1: odd edges
    const int l32 = lane & 31;

    // ---- phase 1: gather-aggregate 8 rows per wave (float4 per half-wave) ----
    for (int rr = 0; rr < 8; ++rr) {
        const int r = w * 8 + rr;
        const int row = r0 + r;
        float4 acc = make_float4(0.f, 0.f, 0.f, 0.f);
        float inv = 0.f;
        if (row < nrows) {
            const int beg = rs[row], end = rs[row + 1];
#pragma unroll 2
            for (int e = beg + half; e < end; e += 2) {
                const int s = csr[e];
                const float4 v = ((const float4*)(hsrc + (size_t)s * HDIM))[l32];
                acc.x += v.x; acc.y += v.y; acc.z += v.z; acc.w += v.w;
            }
            inv = 1.0f / fmaxf((float)(end - beg), 1.0f);
        }
        // combine the two half-waves
        acc.x += __shfl_xor(acc.x, 32);
        acc.y += __shfl_xor(acc.y, 32);
        acc.z += __shfl_xor(acc.z, 32);
        acc.w += __shfl_xor(acc.w, 32);
        if (half == 0) {
            acc.x *= inv; acc.y *= inv; acc.z *= inv; acc.w *= inv;
            *(float4*)(&Xs[r][l32 * 4]) = acc;
        }
    }
    __syncthreads();

    // ---- phase 2: msg = Xs @ W^T (thread = col j, 16 rows) ----
    const int j = tid & 127;
    const int rg = (tid >> 7) * 16;
    float acc[16];
#pragma unroll
    for (int r = 0; r < 16; ++r) acc[r] = 0.f;
    const float4* W4 = (const float4*)(W + (size_t)j * HDIM);
    for (int k4 = 0; k4 < 32; ++k4) {
        const float4 wv = W4[k4];
#pragma unroll
        for (int r = 0; r < 16; ++r) {
            const float4 x = *(const float4*)(&Xs[rg + r][k4 * 4]);
            acc[r] += x.x * wv.x + x.y * wv.y + x.z * wv.z + x.w * wv.w;
        }
    }
    __syncthreads();

    // ---- phase 3: write msg back into the LDS tile ----
#pragma unroll
    for (int r = 0; r < 16; ++r) Xs[rg + r][j] = acc[r];
    __syncthreads();

    // ---- phase 4: residual + LN + ReLU, 8 rows per wave ----
    for (int rr = 0; rr < 8; ++rr) {
        const int r = w * 8 + rr;
        const int row = r0 + r;
        if (row >= nrows) break;  // wave-uniform
        const float2 m = *(const float2*)(&Xs[r][lane * 2]);
        const float2 a = ((const float2*)(hres + (size_t)row * HDIM))[lane];
        float t0 = a.x + m.x, t1 = a.y + m.y;
        float s1 = t0 + t1;
        float s2 = t0 * t0 + t1 * t1;
#pragma unroll
        for (int o = 32; o; o >>= 1) {
            s1 += __shfl_xor(s1, o);
            s2 += __shfl_xor(s2, o);
        }
        const float mu = s1 * (1.0f / 128.0f);
        const float var = s2 * (1.0f / 128.0f) - mu * mu;
        const float rsq = rsqrtf(var + LN_EPS);
        const float2 gg = ((const float2*)g)[lane];
        const float2 bb = ((const float2*)b)[lane];
        const float y0 = fmaxf((t0 - mu) * rsq * gg.x + bb.x, 0.f);
        const float y1 = fmaxf((t1 - mu) * rsq * gg.y + bb.y, 0.f);
        ((float2*)(hout + (size_t)row * HDIM))[lane] = make_float2(y0, y1);
    }
}

// ---------------------------------------------------------------------------
// out[i] = sigmoid(dot(hd[did[i]], wf[0:128]) + dot(hc[cid[i]], wf[128:256]) + bf)
// ---------------------------------------------------------------------------
__global__ void final_kernel(const float* __restrict__ hd, const float* __restrict__ hc,
                             const int* __restrict__ did, const int* __restrict__ cid,
                             const float* __restrict__ wf, const float* __restrict__ bf,
                             float* __restrict__ out, int nb) {
    int row = (blockIdx.x * blockDim.x + threadIdx.x) >> 6;
    int lane = threadIdx.x & 63;
    if (row >= nb) return;
    int d = did[row], c = cid[row];
    float2 x = ((const float2*)(hd + (size_t)d * HDIM))[lane];
    float2 y = ((const float2*)(hc + (size_t)c * HDIM))[lane];
    float2 wa = ((const float2*)wf)[lane];
    float2 wb = ((const float2*)(wf + HDIM))[lane];
    float s = x.x * wa.x + x.y * wa.y + y.x * wb.x + y.y * wb.y;
#pragma unroll
    for (int o = 32; o; o >>= 1) s += __shfl_xor(s, o);
    if (lane == 0) out[row] = 1.0f / (1.0f + expf(-(s + bf[0])));
}

// ---------------------------------------------------------------------------
extern "C" void kernel_launch(void* const* d_in, const int* in_sizes, int n_in,
                              void* d_out, int out_size, void* d_ws, size_t ws_size,
                              hipStream_t stream) {
    const float* emb_drug = (const float*)d_in[0];
    const float* emb_cell = (const float*)d_in[1];
    const float* W_dt     = (const float*)d_in[2];
    const float* W_td     = (const float*)d_in[3];
    const float* g_d      = (const float*)d_in[4];
    const float* b_d      = (const float*)d_in[5];
    const float* g_c      = (const float*)d_in[6];
    const float* b_c      = (const float*)d_in[7];
    const float* Wf       = (const float*)d_in[8];
    const float* bf       = (const float*)d_in[9];
    const int* dt_src     = (const int*)d_in[10];
    const int* dt_dst     = (const int*)d_in[11];
    const int* td_src     = (const int*)d_in[12];
    const int* td_dst     = (const int*)d_in[13];
    const int* drug_ids   = (const int*)d_in[14];
    const int* cell_ids   = (const int*)d_in[15];
    float* out = (float*)d_out;

    // ---- workspace layout ----
    int* cnt_c  = (int*)d_ws;             // 20000   (zeroed)
    int* cnt_d  = cnt_c + NUM_CELL;       // 50000   (zeroed)
    int* cur_c  = cnt_d + NUM_DRUG;       // 20000   (written by scan)
    int* cur_d  = cur_c + NUM_CELL;       // 50000
    int* rs_c   = cur_d + NUM_DRUG;       // 20001
    int* rs_d   = rs_c + (NUM_CELL + 1);  // 50001
    int* csr_dt = rs_d + (NUM_DRUG + 1);  // 600000
    int* csr_td = csr_dt + NE;            // 600000
    size_t off  = (size_t)(csr_td + NE - (int*)d_ws);
    off = (off + 63) & ~(size_t)63;
    float* bufA_d = (float*)d_ws + off;
    float* bufA_c = bufA_d + (size_t)NUM_DRUG * HDIM;
    float* bufB_d = bufA_c + (size_t)NUM_CELL * HDIM;
    float* bufB_c = bufB_d + (size_t)NUM_DRUG * HDIM;

    const dim3 B(256);
    const int layer_blocks = CELL_BLOCKS + DRUG_BLOCKS;

    // ---- build CSR (reused by both layers) ----
    hipMemsetAsync(d_ws, 0, (size_t)(NUM_CELL + NUM_DRUG) * sizeof(int), stream);
    hist_kernel<<<(2 * NE + 255) / 256, B, 0, stream>>>(dt_dst, td_dst, cnt_c, cnt_d, NE);
    scan_kernel<<<2, 1024, 0, stream>>>(cnt_c, rs_c, cur_c, NUM_CELL, cnt_d, rs_d, cur_d, NUM_DRUG);
    fill_kernel<<<(2 * NE + 255) / 256, B, 0, stream>>>(dt_src, dt_dst, td_src, td_dst,
                                                        cur_c, cur_d, csr_dt, csr_td, NE);

    // ---- layer 1: emb_* -> bufA_* ----
    layer_kernel<<<layer_blocks, B, 0, stream>>>(emb_drug, emb_cell,
                                                 csr_dt, rs_c, csr_td, rs_d,
                                                 W_dt, W_td, g_c, b_c, g_d, b_d,
                                                 bufA_c, bufA_d);
    // ---- layer 2: bufA_* -> bufB_* ----
    layer_kernel<<<layer_blocks, B, 0, stream>>>(bufA_d, bufA_c,
                                                 csr_dt, rs_c, csr_td, rs_d,
                                                 W_dt, W_td, g_c, b_c, g_d, b_d,
                                                 bufB_c, bufB_d);

    final_kernel<<<(NB * 64) / 256, B, 0, stream>>>(bufB_d, bufB_c, drug_ids, cell_ids, Wf, bf, out, NB);
}

// Round 4
// 528.930 us; speedup vs baseline: 8.3290x; 1.0804x over previous
//
#include <hip/hip_runtime.h>
#include <math.h>

#define NUM_DRUG 50000
#define NUM_CELL 20000
#define HDIM 128
#define NE 600000
#define NB 4096
#define LN_EPS 1e-5f

#define CELL_BLOCKS ((NUM_CELL + 31) / 32)   // 625
#define DRUG_BLOCKS ((NUM_DRUG + 31) / 32)   // 1563

typedef unsigned short u16;
typedef unsigned int u32;

__device__ __forceinline__ float bflo(u32 u) { return __uint_as_float(u << 16); }
__device__ __forceinline__ float bfhi(u32 u) { return __uint_as_float(u & 0xFFFF0000u); }
__device__ __forceinline__ u32 f2bf1(float f) {
    u32 u = __float_as_uint(f);
    return (u + 0x7FFFu + ((u >> 16) & 1u)) >> 16;  // RNE
}
__device__ __forceinline__ u32 packbf(float lo, float hi) {
    return f2bf1(lo) | (f2bf1(hi) << 16);
}

// ---------------------------------------------------------------------------
// histogram of dst indices for both relations
// ---------------------------------------------------------------------------
__global__ void hist_kernel(const int* __restrict__ dt_dst, const int* __restrict__ td_dst,
                            int* __restrict__ cnt_c, int* __restrict__ cnt_d, int ne) {
    int t = blockIdx.x * blockDim.x + threadIdx.x;
    if (t < ne) {
        atomicAdd(&cnt_c[dt_dst[t]], 1);
    } else if (t < 2 * ne) {
        atomicAdd(&cnt_d[td_dst[t - ne]], 1);
    }
}

// ---------------------------------------------------------------------------
// single-block exclusive scan; writes rs (n+1) and cur (=rs copy)
// ---------------------------------------------------------------------------
__global__ void scan_kernel(const int* __restrict__ cnt0, int* __restrict__ rs0, int* __restrict__ cur0, int n0,
                            const int* __restrict__ cnt1, int* __restrict__ rs1, int* __restrict__ cur1, int n1) {
    const int* cnt = blockIdx.x ? cnt1 : cnt0;
    int* rs  = blockIdx.x ? rs1 : rs0;
    int* cur = blockIdx.x ? cur1 : cur0;
    int n = blockIdx.x ? n1 : n0;

    __shared__ int wsum[16];
    __shared__ int s_carry;
    const int tid = threadIdx.x;
    const int lane = tid & 63;
    const int w = tid >> 6;
    if (tid == 0) s_carry = 0;
    __syncthreads();

    for (int base = 0; base < n; base += 1024) {
        int v = (base + tid < n) ? cnt[base + tid] : 0;
        int x = v;
#pragma unroll
        for (int o = 1; o < 64; o <<= 1) {
            int y = __shfl_up(x, o);
            if (lane >= o) x += y;
        }
        if (lane == 63) wsum[w] = x;
        __syncthreads();
        if (w == 0 && lane < 16) {
            int y = wsum[lane];
#pragma unroll
            for (int o = 1; o < 16; o <<= 1) {
                int z = __shfl_up(y, o);
                if (lane >= o) y += z;
            }
            wsum[lane] = y;
        }
        __syncthreads();
        int total = wsum[15];
        int excl = s_carry + (w ? wsum[w - 1] : 0) + x - v;
        if (base + tid < n) { rs[base + tid] = excl; cur[base + tid] = excl; }
        __syncthreads();
        if (tid == 0) s_carry += total;
        __syncthreads();
    }
    if (tid == 0) rs[n] = s_carry;
}

// ---------------------------------------------------------------------------
// fill CSR: csr[atomicAdd(&cur[dst],1)] = src
// ---------------------------------------------------------------------------
__global__ void fill_kernel(const int* __restrict__ dt_src, const int* __restrict__ dt_dst,
                            const int* __restrict__ td_src, const int* __restrict__ td_dst,
                            int* __restrict__ cur_c, int* __restrict__ cur_d,
                            int* __restrict__ csr_dt, int* __restrict__ csr_td, int ne) {
    int t = blockIdx.x * blockDim.x + threadIdx.x;
    if (t < ne) {
        int s = dt_src[t];
        int p = atomicAdd(&cur_c[dt_dst[t]], 1);
        csr_dt[p] = s;
    } else if (t < 2 * ne) {
        int e = t - ne;
        int s = td_src[e];
        int p = atomicAdd(&cur_d[td_dst[e]], 1);
        csr_td[p] = s;
    }
}

// ---------------------------------------------------------------------------
// cast fp32 embedding tables to bf16 (8 elems per thread)
// ---------------------------------------------------------------------------
__global__ void cast_kernel(const float* __restrict__ ed, const float* __restrict__ ec,
                            u16* __restrict__ e16d, u16* __restrict__ e16c) {
    const int ND8 = NUM_DRUG * HDIM / 8;
    const int NC8 = NUM_CELL * HDIM / 8;
    int t = blockIdx.x * blockDim.x + threadIdx.x;
    const float4* src;
    u16* dst;
    int i;
    if (t < ND8) { src = (const float4*)ed; dst = e16d; i = t; }
    else if (t < ND8 + NC8) { src = (const float4*)ec; dst = e16c; i = t - ND8; }
    else return;
    float4 v0 = src[2 * i], v1 = src[2 * i + 1];
    uint4 o;
    o.x = packbf(v0.x, v0.y);
    o.y = packbf(v0.z, v0.w);
    o.z = packbf(v1.x, v1.y);
    o.w = packbf(v1.z, v1.w);
    ((uint4*)dst)[i] = o;
}

// ---------------------------------------------------------------------------
// fused layer: bf16 mean-gather -> @W^T -> residual(fp32)+LN+ReLU
// quarter-wave (16 lanes x 16B) covers one 256B bf16 row -> 4 edges per
// wave-level load instruction. 256 threads, 32 dst rows/block, 16KB LDS.
// ---------------------------------------------------------------------------
__global__ __launch_bounds__(256, 8)
void layer_kernel(const u16* __restrict__ s16_d, const u16* __restrict__ s16_c,
                  const float* __restrict__ res_d, const float* __restrict__ res_c,
                  const int* __restrict__ csr_dt, const int* __restrict__ rs_c,
                  const int* __restrict__ csr_td, const int* __restrict__ rs_d,
                  const float* __restrict__ W_dt, const float* __restrict__ W_td,
                  const float* __restrict__ g_c, const float* __restrict__ b_c,
                  const float* __restrict__ g_d, const float* __restrict__ b_d,
                  float* __restrict__ o32_d, float* __restrict__ o32_c,
                  u16* __restrict__ o16_d, u16* __restrict__ o16_c) {
    __shared__ __align__(16) float Xs[32][128];

    const bool isCell = blockIdx.x < CELL_BLOCKS;
    const u16* hsrc = isCell ? s16_d : s16_c;
    const float* hres = isCell ? res_c : res_d;
    const int* csr = isCell ? csr_dt : csr_td;
    const int* rs  = isCell ? rs_c : rs_d;
    const float* W = isCell ? W_dt : W_td;
    const float* g = isCell ? g_c : g_d;
    const float* b = isCell ? b_c : b_d;
    float* o32 = isCell ? o32_c : o32_d;
    u16* o16 = isCell ? o16_c : o16_d;
    const int nrows = isCell ? NUM_CELL : NUM_DRUG;
    const int r0 = (isCell ? blockIdx.x : blockIdx.x - CELL_BLOCKS) * 32;

    const int tid = threadIdx.x;
    const int lane = tid & 63;
    const int w = tid >> 6;
    const int q = lane >> 4;     // quarter 0..3: edge phase
    const int l16 = lane & 15;   // 16B chunk within row

    // ---- phase 1: gather-aggregate 8 rows per wave ----
    for (int rr = 0; rr < 8; ++rr) {
        const int r = w * 8 + rr;
        const int row = r0 + r;
        float a0 = 0.f, a1 = 0.f, a2 = 0.f, a3 = 0.f, a4 = 0.f, a5 = 0.f, a6 = 0.f, a7 = 0.f;
        float inv = 0.f;
        if (row < nrows) {
            const int beg = rs[row], end = rs[row + 1];
#pragma unroll 2
            for (int e = beg + q; e < end; e += 4) {
                const uint4 u = *((const uint4*)(hsrc + (size_t)csr[e] * HDIM) + l16);
                a0 += bflo(u.x); a1 += bfhi(u.x);
                a2 += bflo(u.y); a3 += bfhi(u.y);
                a4 += bflo(u.z); a5 += bfhi(u.z);
                a6 += bflo(u.w); a7 += bfhi(u.w);
            }
            inv = 1.0f / fmaxf((float)(end - beg), 1.0f);
        }
        // combine the 4 quarters
        a0 += __shfl_xor(a0, 16); a1 += __shfl_xor(a1, 16);
        a2 += __shfl_xor(a2, 16); a3 += __shfl_xor(a3, 16);
        a4 += __shfl_xor(a4, 16); a5 += __shfl_xor(a5, 16);
        a6 += __shfl_xor(a6, 16); a7 += __shfl_xor(a7, 16);
        a0 += __shfl_xor(a0, 32); a1 += __shfl_xor(a1, 32);
        a2 += __shfl_xor(a2, 32); a3 += __shfl_xor(a3, 32);
        a4 += __shfl_xor(a4, 32); a5 += __shfl_xor(a5, 32);
        a6 += __shfl_xor(a6, 32); a7 += __shfl_xor(a7, 32);
        if (lane < 16) {
            *(float4*)(&Xs[r][l16 * 8])     = make_float4(a0 * inv, a1 * inv, a2 * inv, a3 * inv);
            *(float4*)(&Xs[r][l16 * 8 + 4]) = make_float4(a4 * inv, a5 * inv, a6 * inv, a7 * inv);
        }
    }
    __syncthreads();

    // ---- phase 2: msg = Xs @ W^T ----
    const int j = tid & 127;
    const int rg = (tid >> 7) * 16;
    float acc[16];
#pragma unroll
    for (int r = 0; r < 16; ++r) acc[r] = 0.f;
    const float4* W4 = (const float4*)(W + (size_t)j * HDIM);
    for (int k4 = 0; k4 < 32; ++k4) {
        const float4 wv = W4[k4];
#pragma unroll
        for (int r = 0; r < 16; ++r) {
            const float4 x = *(const float4*)(&Xs[rg + r][k4 * 4]);
            acc[r] += x.x * wv.x + x.y * wv.y + x.z * wv.z + x.w * wv.w;
        }
    }
    __syncthreads();

    // ---- phase 3: msg back into LDS ----
#pragma unroll
    for (int r = 0; r < 16; ++r) Xs[rg + r][j] = acc[r];
    __syncthreads();

    // ---- phase 4: residual + LN + ReLU ----
    for (int rr = 0; rr < 8; ++rr) {
        const int r = w * 8 + rr;
        const int row = r0 + r;
        if (row >= nrows) break;  // wave-uniform
        const float2 m = *(const float2*)(&Xs[r][lane * 2]);
        const float2 a = ((const float2*)(hres + (size_t)row * HDIM))[lane];
        float t0 = a.x + m.x, t1 = a.y + m.y;
        float s1 = t0 + t1;
        float s2 = t0 * t0 + t1 * t1;
#pragma unroll
        for (int o = 32; o; o >>= 1) {
            s1 += __shfl_xor(s1, o);
            s2 += __shfl_xor(s2, o);
        }
        const float mu = s1 * (1.0f / 128.0f);
        const float var = s2 * (1.0f / 128.0f) - mu * mu;
        const float rsq = rsqrtf(var + LN_EPS);
        const float2 gg = ((const float2*)g)[lane];
        const float2 bb = ((const float2*)b)[lane];
        const float y0 = fmaxf((t0 - mu) * rsq * gg.x + bb.x, 0.f);
        const float y1 = fmaxf((t1 - mu) * rsq * gg.y + bb.y, 0.f);
        if (o32) ((float2*)(o32 + (size_t)row * HDIM))[lane] = make_float2(y0, y1);
        ((u32*)(o16 + (size_t)row * HDIM))[lane] = packbf(y0, y1);
    }
}

// ---------------------------------------------------------------------------
// out[i] = sigmoid(dot over bf16 rows + bias)
// ---------------------------------------------------------------------------
__global__ void final_kernel(const u16* __restrict__ hd16, const u16* __restrict__ hc16,
                             const int* __restrict__ did, const int* __restrict__ cid,
                             const float* __restrict__ wf, const float* __restrict__ bf_,
                             float* __restrict__ out, int nb) {
    int row = (blockIdx.x * blockDim.x + threadIdx.x) >> 6;
    int lane = threadIdx.x & 63;
    if (row >= nb) return;
    int d = did[row], c = cid[row];
    u32 ud = ((const u32*)(hd16 + (size_t)d * HDIM))[lane];
    u32 uc = ((const u32*)(hc16 + (size_t)c * HDIM))[lane];
    float2 wa = ((const float2*)wf)[lane];
    float2 wb = ((const float2*)(wf + HDIM))[lane];
    float s = bflo(ud) * wa.x + bfhi(ud) * wa.y + bflo(uc) * wb.x + bfhi(uc) * wb.y;
#pragma unroll
    for (int o = 32; o; o >>= 1) s += __shfl_xor(s, o);
    if (lane == 0) out[row] = 1.0f / (1.0f + expf(-(s + bf_[0])));
}

// ---------------------------------------------------------------------------
extern "C" void kernel_launch(void* const* d_in, const int* in_sizes, int n_in,
                              void* d_out, int out_size, void* d_ws, size_t ws_size,
                              hipStream_t stream) {
    const float* emb_drug = (const float*)d_in[0];
    const float* emb_cell = (const float*)d_in[1];
    const float* W_dt     = (const float*)d_in[2];
    const float* W_td     = (const float*)d_in[3];
    const float* g_d      = (const float*)d_in[4];
    const float* b_d      = (const float*)d_in[5];
    const float* g_c      = (const float*)d_in[6];
    const float* b_c      = (const float*)d_in[7];
    const float* Wf       = (const float*)d_in[8];
    const float* bf       = (const float*)d_in[9];
    const int* dt_src     = (const int*)d_in[10];
    const int* dt_dst     = (const int*)d_in[11];
    const int* td_src     = (const int*)d_in[12];
    const int* td_dst     = (const int*)d_in[13];
    const int* drug_ids   = (const int*)d_in[14];
    const int* cell_ids   = (const int*)d_in[15];
    float* out = (float*)d_out;

    // ---- workspace layout (~77 MB, matches previously proven footprint) ----
    int* cnt_c  = (int*)d_ws;             // zeroed
    int* cnt_d  = cnt_c + NUM_CELL;       // zeroed
    int* cur_c  = cnt_d + NUM_DRUG;
    int* cur_d  = cur_c + NUM_CELL;
    int* rs_c   = cur_d + NUM_DRUG;
    int* rs_d   = rs_c + (NUM_CELL + 1);
    int* csr_dt = rs_d + (NUM_DRUG + 1);
    int* csr_td = csr_dt + NE;
    size_t off  = (size_t)(csr_td + NE - (int*)d_ws);
    off = (off + 63) & ~(size_t)63;
    float* fbase = (float*)d_ws + off;
    float* fA_d  = fbase;                                   // 6.40M f32
    float* fA_c  = fA_d + (size_t)NUM_DRUG * HDIM;          // 2.56M f32
    u16* a16_d   = (u16*)(fA_c + (size_t)NUM_CELL * HDIM);  // 6.4M bf16
    u16* a16_c   = a16_d + (size_t)NUM_DRUG * HDIM;         // 2.56M bf16
    u16* e16_d   = a16_c + (size_t)NUM_CELL * HDIM;         // 6.4M bf16 (slot X)
    u16* e16_c   = e16_d + (size_t)NUM_DRUG * HDIM;         // 2.56M bf16 (slot X)
    u16* b16_d   = e16_d;  // alias: emb-bf16 dead after layer 1
    u16* b16_c   = e16_c;

    const dim3 B(256);
    const int layer_blocks = CELL_BLOCKS + DRUG_BLOCKS;
    const int cast_threads = (NUM_DRUG + NUM_CELL) * HDIM / 8;

    // ---- build CSR (reused by both layers) ----
    hipMemsetAsync(d_ws, 0, (size_t)(NUM_CELL + NUM_DRUG) * sizeof(int), stream);
    hist_kernel<<<(2 * NE + 255) / 256, B, 0, stream>>>(dt_dst, td_dst, cnt_c, cnt_d, NE);
    scan_kernel<<<2, 1024, 0, stream>>>(cnt_c, rs_c, cur_c, NUM_CELL, cnt_d, rs_d, cur_d, NUM_DRUG);
    fill_kernel<<<(2 * NE + 255) / 256, B, 0, stream>>>(dt_src, dt_dst, td_src, td_dst,
                                                        cur_c, cur_d, csr_dt, csr_td, NE);
    cast_kernel<<<(cast_threads + 255) / 256, B, 0, stream>>>(emb_drug, emb_cell, e16_d, e16_c);

    // ---- layer 1: gather e16, residual emb fp32 -> fA (f32) + a16 (bf16) ----
    layer_kernel<<<layer_blocks, B, 0, stream>>>(e16_d, e16_c, emb_drug, emb_cell,
                                                 csr_dt, rs_c, csr_td, rs_d,
                                                 W_dt, W_td, g_c, b_c, g_d, b_d,
                                                 fA_d, fA_c, a16_d, a16_c);
    // ---- layer 2: gather a16, residual fA fp32 -> b16 (bf16 only) ----
    layer_kernel<<<layer_blocks, B, 0, stream>>>(a16_d, a16_c, fA_d, fA_c,
                                                 csr_dt, rs_c, csr_td, rs_d,
                                                 W_dt, W_td, g_c, b_c, g_d, b_d,
                                                 nullptr, nullptr, b16_d, b16_c);

    final_kernel<<<(NB * 64) / 256, B, 0, stream>>>(b16_d, b16_c, drug_ids, cell_ids, Wf, bf, out, NB);
}

// Round 5
// 506.861 us; speedup vs baseline: 8.6917x; 1.0435x over previous
//
#include <hip/hip_runtime.h>
#include <math.h>

#define NUM_DRUG 50000
#define NUM_CELL 20000
#define HDIM 128
#define NE 600000
#define NB 4096
#define LN_EPS 1e-5f
#define LDA 132   // padded LDS row (floats)

#define CELL_BLOCKS ((NUM_CELL + 31) / 32)   // 625
#define DRUG_BLOCKS ((NUM_DRUG + 31) / 32)   // 1563
#define CAST_BLOCKS ((NUM_DRUG + NUM_CELL) * HDIM / 8 / 256)  // 4375
#define HIST_BLOCKS ((2 * NE + 255) / 256)   // 4688

typedef unsigned short u16;
typedef unsigned int u32;

__device__ __forceinline__ float bflo(u32 u) { return __uint_as_float(u << 16); }
__device__ __forceinline__ float bfhi(u32 u) { return __uint_as_float(u & 0xFFFF0000u); }
__device__ __forceinline__ u32 f2bf1(float f) {
    u32 u = __float_as_uint(f);
    return (u + 0x7FFFu + ((u >> 16) & 1u)) >> 16;  // RNE
}
__device__ __forceinline__ u32 packbf(float lo, float hi) {
    return f2bf1(lo) | (f2bf1(hi) << 16);
}

#define ACC8(u) do { \
    a0 += bflo((u).x); a1 += bfhi((u).x); a2 += bflo((u).y); a3 += bfhi((u).y); \
    a4 += bflo((u).z); a5 += bfhi((u).z); a6 += bflo((u).w); a7 += bfhi((u).w); } while (0)

// ---------------------------------------------------------------------------
// prep: blocks [0,CAST_BLOCKS) cast fp32 emb -> bf16; rest histogram dst ids
// ---------------------------------------------------------------------------
__global__ void prep_kernel(const float* __restrict__ ed, const float* __restrict__ ec,
                            u16* __restrict__ e16d, u16* __restrict__ e16c,
                            const int* __restrict__ dt_dst, const int* __restrict__ td_dst,
                            int* __restrict__ cnt_c, int* __restrict__ cnt_d) {
    if (blockIdx.x < CAST_BLOCKS) {
        const int ND8 = NUM_DRUG * HDIM / 8;
        int t = blockIdx.x * blockDim.x + threadIdx.x;
        const float4* src;
        u16* dst;
        int i;
        if (t < ND8) { src = (const float4*)ed; dst = e16d; i = t; }
        else { src = (const float4*)ec; dst = e16c; i = t - ND8; }
        float4 v0 = src[2 * i], v1 = src[2 * i + 1];
        uint4 o;
        o.x = packbf(v0.x, v0.y);
        o.y = packbf(v0.z, v0.w);
        o.z = packbf(v1.x, v1.y);
        o.w = packbf(v1.z, v1.w);
        ((uint4*)dst)[i] = o;
    } else {
        int t = (blockIdx.x - CAST_BLOCKS) * blockDim.x + threadIdx.x;
        if (t < NE) {
            atomicAdd(&cnt_c[dt_dst[t]], 1);
        } else if (t < 2 * NE) {
            atomicAdd(&cnt_d[td_dst[t - NE]], 1);
        }
    }
}

// ---------------------------------------------------------------------------
// single-block exclusive scan; writes rs (n+1) and cur (=rs copy)
// ---------------------------------------------------------------------------
__global__ void scan_kernel(const int* __restrict__ cnt0, int* __restrict__ rs0, int* __restrict__ cur0, int n0,
                            const int* __restrict__ cnt1, int* __restrict__ rs1, int* __restrict__ cur1, int n1) {
    const int* cnt = blockIdx.x ? cnt1 : cnt0;
    int* rs  = blockIdx.x ? rs1 : rs0;
    int* cur = blockIdx.x ? cur1 : cur0;
    int n = blockIdx.x ? n1 : n0;

    __shared__ int wsum[16];
    __shared__ int s_carry;
    const int tid = threadIdx.x;
    const int lane = tid & 63;
    const int w = tid >> 6;
    if (tid == 0) s_carry = 0;
    __syncthreads();

    for (int base = 0; base < n; base += 1024) {
        int v = (base + tid < n) ? cnt[base + tid] : 0;
        int x = v;
#pragma unroll
        for (int o = 1; o < 64; o <<= 1) {
            int y = __shfl_up(x, o);
            if (lane >= o) x += y;
        }
        if (lane == 63) wsum[w] = x;
        __syncthreads();
        if (w == 0 && lane < 16) {
            int y = wsum[lane];
#pragma unroll
            for (int o = 1; o < 16; o <<= 1) {
                int z = __shfl_up(y, o);
                if (lane >= o) y += z;
            }
            wsum[lane] = y;
        }
        __syncthreads();
        int total = wsum[15];
        int excl = s_carry + (w ? wsum[w - 1] : 0) + x - v;
        if (base + tid < n) { rs[base + tid] = excl; cur[base + tid] = excl; }
        __syncthreads();
        if (tid == 0) s_carry += total;
        __syncthreads();
    }
    if (tid == 0) rs[n] = s_carry;
}

// ---------------------------------------------------------------------------
// fill CSR (u16 src ids): csr[atomicAdd(&cur[dst],1)] = src
// ---------------------------------------------------------------------------
__global__ void fill_kernel(const int* __restrict__ dt_src, const int* __restrict__ dt_dst,
                            const int* __restrict__ td_src, const int* __restrict__ td_dst,
                            int* __restrict__ cur_c, int* __restrict__ cur_d,
                            u16* __restrict__ csr_dt, u16* __restrict__ csr_td, int ne) {
    int t = blockIdx.x * blockDim.x + threadIdx.x;
    if (t < ne) {
        int s = dt_src[t];
        int p = atomicAdd(&cur_c[dt_dst[t]], 1);
        csr_dt[p] = (u16)s;
    } else if (t < 2 * ne) {
        int e = t - ne;
        int s = td_src[e];
        int p = atomicAdd(&cur_d[td_dst[e]], 1);
        csr_td[p] = (u16)s;
    }
}

// ---------------------------------------------------------------------------
// fused layer, all-bf16: quarter-owns-row mean-gather (unroll-4, 16 edges in
// flight per wave) -> @W^T in fp32 -> bf16 residual + LN + ReLU -> bf16 out.
// 256 threads, 32 dst rows/block, padded 16.9 KB LDS tile.
// ---------------------------------------------------------------------------
__global__ __launch_bounds__(256, 8)
void layer_kernel(const u16* __restrict__ s16_d, const u16* __restrict__ s16_c,
                  const u16* __restrict__ csr_dt, const int* __restrict__ rs_c,
                  const u16* __restrict__ csr_td, const int* __restrict__ rs_d,
                  const float* __restrict__ W_dt, const float* __restrict__ W_td,
                  const float* __restrict__ g_c, const float* __restrict__ b_c,
                  const float* __restrict__ g_d, const float* __restrict__ b_d,
                  u16* __restrict__ o16_d, u16* __restrict__ o16_c) {
    __shared__ __align__(16) float Xs[32][LDA];

    const bool isCell = blockIdx.x < CELL_BLOCKS;
    const u16* hsrc = isCell ? s16_d : s16_c;   // gather (other side)
    const u16* hres = isCell ? s16_c : s16_d;   // residual (own side)
    const u16* csr = isCell ? csr_dt : csr_td;
    const int* rs  = isCell ? rs_c : rs_d;
    const float* W = isCell ? W_dt : W_td;
    const float* g = isCell ? g_c : g_d;
    const float* b = isCell ? b_c : b_d;
    u16* o16 = isCell ? o16_c : o16_d;
    const int nrows = isCell ? NUM_CELL : NUM_DRUG;
    const int r0 = (isCell ? blockIdx.x : blockIdx.x - CELL_BLOCKS) * 32;

    const int tid = threadIdx.x;
    const int lane = tid & 63;
    const int w = tid >> 6;
    const int q = lane >> 4;     // quarter owns one row per phase
    const int l16 = lane & 15;   // 16B chunk within the row

    // ---- phase 1: gather-aggregate; each quarter owns rows w*8+ph*4+q ----
    for (int ph = 0; ph < 2; ++ph) {
        const int r = w * 8 + ph * 4 + q;
        const int row = r0 + r;
        int beg = 0, deg = 0;
        if (row < nrows) { beg = rs[row]; deg = rs[row + 1] - beg; }
        if (deg <= 0) beg = 0;
        const int last = (deg > 0) ? deg - 1 : 0;
        int dmax = deg;
        dmax = max(dmax, __shfl_xor(dmax, 16));
        dmax = max(dmax, __shfl_xor(dmax, 32));

        float a0 = 0.f, a1 = 0.f, a2 = 0.f, a3 = 0.f, a4 = 0.f, a5 = 0.f, a6 = 0.f, a7 = 0.f;
        int i = 0;
        for (; i + 3 < dmax; i += 4) {
            const int i0 = (i     < deg) ? i     : last;
            const int i1 = (i + 1 < deg) ? i + 1 : last;
            const int i2 = (i + 2 < deg) ? i + 2 : last;
            const int i3 = (i + 3 < deg) ? i + 3 : last;
            uint4 u0 = *((const uint4*)(hsrc + (size_t)csr[beg + i0] * HDIM) + l16);
            uint4 u1 = *((const uint4*)(hsrc + (size_t)csr[beg + i1] * HDIM) + l16);
            uint4 u2 = *((const uint4*)(hsrc + (size_t)csr[beg + i2] * HDIM) + l16);
            uint4 u3 = *((const uint4*)(hsrc + (size_t)csr[beg + i3] * HDIM) + l16);
            if (i     >= deg) { u0.x = u0.y = u0.z = u0.w = 0u; }
            if (i + 1 >= deg) { u1.x = u1.y = u1.z = u1.w = 0u; }
            if (i + 2 >= deg) { u2.x = u2.y = u2.z = u2.w = 0u; }
            if (i + 3 >= deg) { u3.x = u3.y = u3.z = u3.w = 0u; }
            ACC8(u0); ACC8(u1); ACC8(u2); ACC8(u3);
        }
        for (; i < dmax; ++i) {
            const int ii = (i < deg) ? i : last;
            uint4 u = *((const uint4*)(hsrc + (size_t)csr[beg + ii] * HDIM) + l16);
            if (i >= deg) { u.x = u.y = u.z = u.w = 0u; }
            ACC8(u);
        }
        const float inv = 1.0f / fmaxf((float)deg, 1.0f);
        *(float4*)(&Xs[r][l16 * 8])     = make_float4(a0 * inv, a1 * inv, a2 * inv, a3 * inv);
        *(float4*)(&Xs[r][l16 * 8 + 4]) = make_float4(a4 * inv, a5 * inv, a6 * inv, a7 * inv);
    }
    __syncthreads();

    // ---- phase 2: msg = Xs @ W^T (thread = col j, 16 rows; Xs reads broadcast) ----
    const int j = tid & 127;
    const int rg = (tid >> 7) * 16;
    float acc[16];
#pragma unroll
    for (int r = 0; r < 16; ++r) acc[r] = 0.f;
    const float4* W4 = (const float4*)(W + (size_t)j * HDIM);
    for (int k4 = 0; k4 < 32; ++k4) {
        const float4 wv = W4[k4];
#pragma unroll
        for (int r = 0; r < 16; ++r) {
            const float4 x = *(const float4*)(&Xs[rg + r][k4 * 4]);
            acc[r] += x.x * wv.x + x.y * wv.y + x.z * wv.z + x.w * wv.w;
        }
    }
    __syncthreads();

    // ---- phase 3: msg back into LDS ----
#pragma unroll
    for (int r = 0; r < 16; ++r) Xs[rg + r][j] = acc[r];
    __syncthreads();

    // ---- phase 4: bf16 residual + LN + ReLU -> bf16 out ----
    for (int rr = 0; rr < 8; ++rr) {
        const int r = w * 8 + rr;
        const int row = r0 + r;
        if (row >= nrows) break;  // wave-uniform
        const float2 m = *(const float2*)(&Xs[r][lane * 2]);
        const u32 ur = ((const u32*)(hres + (size_t)row * HDIM))[lane];
        float t0 = bflo(ur) + m.x, t1 = bfhi(ur) + m.y;
        float s1 = t0 + t1;
        float s2 = t0 * t0 + t1 * t1;
#pragma unroll
        for (int o = 32; o; o >>= 1) {
            s1 += __shfl_xor(s1, o);
            s2 += __shfl_xor(s2, o);
        }
        const float mu = s1 * (1.0f / 128.0f);
        const float var = s2 * (1.0f / 128.0f) - mu * mu;
        const float rsq = rsqrtf(var + LN_EPS);
        const float2 gg = ((const float2*)g)[lane];
        const float2 bb = ((const float2*)b)[lane];
        const float y0 = fmaxf((t0 - mu) * rsq * gg.x + bb.x, 0.f);
        const float y1 = fmaxf((t1 - mu) * rsq * gg.y + bb.y, 0.f);
        ((u32*)(o16 + (size_t)row * HDIM))[lane] = packbf(y0, y1);
    }
}

// ---------------------------------------------------------------------------
// out[i] = sigmoid(dot over bf16 rows + bias)
// ---------------------------------------------------------------------------
__global__ void final_kernel(const u16* __restrict__ hd16, const u16* __restrict__ hc16,
                             const int* __restrict__ did, const int* __restrict__ cid,
                             const float* __restrict__ wf, const float* __restrict__ bf_,
                             float* __restrict__ out, int nb) {
    int row = (blockIdx.x * blockDim.x + threadIdx.x) >> 6;
    int lane = threadIdx.x & 63;
    if (row >= nb) return;
    int d = did[row], c = cid[row];
    u32 ud = ((const u32*)(hd16 + (size_t)d * HDIM))[lane];
    u32 uc = ((const u32*)(hc16 + (size_t)c * HDIM))[lane];
    float2 wa = ((const float2*)wf)[lane];
    float2 wb = ((const float2*)(wf + HDIM))[lane];
    float s = bflo(ud) * wa.x + bfhi(ud) * wa.y + bflo(uc) * wb.x + bfhi(uc) * wb.y;
#pragma unroll
    for (int o = 32; o; o >>= 1) s += __shfl_xor(s, o);
    if (lane == 0) out[row] = 1.0f / (1.0f + expf(-(s + bf_[0])));
}

// ---------------------------------------------------------------------------
extern "C" void kernel_launch(void* const* d_in, const int* in_sizes, int n_in,
                              void* d_out, int out_size, void* d_ws, size_t ws_size,
                              hipStream_t stream) {
    const float* emb_drug = (const float*)d_in[0];
    const float* emb_cell = (const float*)d_in[1];
    const float* W_dt     = (const float*)d_in[2];
    const float* W_td     = (const float*)d_in[3];
    const float* g_d      = (const float*)d_in[4];
    const float* b_d      = (const float*)d_in[5];
    const float* g_c      = (const float*)d_in[6];
    const float* b_c      = (const float*)d_in[7];
    const float* Wf       = (const float*)d_in[8];
    const float* bf       = (const float*)d_in[9];
    const int* dt_src     = (const int*)d_in[10];
    const int* dt_dst     = (const int*)d_in[11];
    const int* td_src     = (const int*)d_in[12];
    const int* td_dst     = (const int*)d_in[13];
    const int* drug_ids   = (const int*)d_in[14];
    const int* cell_ids   = (const int*)d_in[15];
    float* out = (float*)d_out;

    // ---- workspace layout (~39 MB) ----
    int* cnt_c  = (int*)d_ws;             // zeroed
    int* cnt_d  = cnt_c + NUM_CELL;       // zeroed
    int* cur_c  = cnt_d + NUM_DRUG;
    int* cur_d  = cur_c + NUM_CELL;
    int* rs_c   = cur_d + NUM_DRUG;
    int* rs_d   = rs_c + (NUM_CELL + 1);
    u16* csr_dt = (u16*)(rs_d + (NUM_DRUG + 1));
    u16* csr_td = csr_dt + NE;
    size_t off = ((size_t)((char*)(csr_td + NE) - (char*)d_ws) + 255) & ~(size_t)255;
    u16* e16_d = (u16*)((char*)d_ws + off);           // layer-1 gather tables
    u16* e16_c = e16_d + (size_t)NUM_DRUG * HDIM;
    u16* a16_d = e16_c + (size_t)NUM_CELL * HDIM;     // layer-1 outputs
    u16* a16_c = a16_d + (size_t)NUM_DRUG * HDIM;
    u16* b16_d = e16_d;  // layer-2 outputs alias dead e16 slot
    u16* b16_c = e16_c;

    const dim3 B(256);
    const int layer_blocks = CELL_BLOCKS + DRUG_BLOCKS;

    // ---- build CSR + bf16 cast ----
    hipMemsetAsync(d_ws, 0, (size_t)(NUM_CELL + NUM_DRUG) * sizeof(int), stream);
    prep_kernel<<<CAST_BLOCKS + HIST_BLOCKS, B, 0, stream>>>(emb_drug, emb_cell, e16_d, e16_c,
                                                             dt_dst, td_dst, cnt_c, cnt_d);
    scan_kernel<<<2, 1024, 0, stream>>>(cnt_c, rs_c, cur_c, NUM_CELL, cnt_d, rs_d, cur_d, NUM_DRUG);
    fill_kernel<<<HIST_BLOCKS, B, 0, stream>>>(dt_src, dt_dst, td_src, td_dst,
                                               cur_c, cur_d, csr_dt, csr_td, NE);

    // ---- layer 1: gather/residual e16 -> a16 ----
    layer_kernel<<<layer_blocks, B, 0, stream>>>(e16_d, e16_c,
                                                 csr_dt, rs_c, csr_td, rs_d,
                                                 W_dt, W_td, g_c, b_c, g_d, b_d,
                                                 a16_d, a16_c);
    // ---- layer 2: gather/residual a16 -> b16 ----
    layer_kernel<<<layer_blocks, B, 0, stream>>>(a16_d, a16_c,
                                                 csr_dt, rs_c, csr_td, rs_d,
                                                 W_dt, W_td, g_c, b_c, g_d, b_d,
                                                 b16_d, b16_c);

    final_kernel<<<(NB * 64) / 256, B, 0, stream>>>(b16_d, b16_c, drug_ids, cell_ids, Wf, bf, out, NB);
}